// Round 1
// 725.878 us; speedup vs baseline: 1.1903x; 1.1903x over previous
//
#include <hip/hip_runtime.h>

// MSA_53979148976474 — Swin windowed MSA, per-head-per-wave restructure.
// R4 theory: old kernel was latency/serialization bound (MfmaUtil 5.7%,
// occupancy 18%, 7 barriers, x re-converted 6x after the compiler sank the
// 96-VGPR afr array). New structure: wave h owns head h end-to-end.
//  - QKV via operand-SWAPPED mfma (A=weights, B=x) so outputs land with
//    token on l15; q/k/v/P redistributions are in-register cross-quad
//    ds_bpermute gathers (helper xpose), zero LDS staging.
//  - x staged fp32->bf16 ONCE into LDS [64][200] (coalesced f32x4);
//    o-buffer aliases it after a barrier.  LDS 78848 -> 25600 B.
//  - softmax: lane-local over 16 values + 2 cross-quad shfl_xor (was 128
//    chained width-16 shuffles/wave).
//  - rel-pos bias pre-gathered by prep kernel into register layout
//    [h][mt][nt][lane][r] -> one f32x4 load per tile.
//  - barriers 7 -> 3.
// One block = one window; 384 thr = 6 waves = 1 wave/head.

#define NTOK 64
#define DIM  192
#define HEADS 6
#define NWIN 4096

typedef short short8  __attribute__((ext_vector_type(8)));
typedef short short4v __attribute__((ext_vector_type(4)));
typedef float f32x4   __attribute__((ext_vector_type(4)));
typedef unsigned int u32;
typedef u32 u32x2 __attribute__((ext_vector_type(2)));
typedef u32 u32x4 __attribute__((ext_vector_type(4)));

#define QW_SHORTS  110592          // 576*192
#define W_SHORTS   147456          // + 192*192
#define BIAS_OFF_B 294912          // byte offset of bias_fr in ws
#define WS_NEEDED  (294912 + 98304)

__device__ __forceinline__ short f2bf(float f) {
    unsigned u = __builtin_bit_cast(unsigned, f);
    unsigned r = (u + 0x7fffu + ((u >> 16) & 1u)) >> 16;  // RNE
    return (short)r;
}
__device__ __forceinline__ u32 pkbf(float lo, float hi) {
    u32 d;
    asm("v_cvt_pk_bf16_f32 %0, %1, %2" : "=v"(d) : "v"(lo), "v"(hi));
    return d;
}
__device__ __forceinline__ short8 ld_cvt8(const float* p) {
    f32x4 a = *(const f32x4*)p;
    f32x4 b = *(const f32x4*)(p + 4);
    u32x4 w;
    w[0] = pkbf(a[0], a[1]); w[1] = pkbf(a[2], a[3]);
    w[2] = pkbf(b[0], b[1]); w[3] = pkbf(b[2], b[3]);
    return __builtin_bit_cast(short8, w);
}

// ---- prep: weights fp32->bf16 + rel-pos bias pre-gather into frag layout ----
__global__ void prep(const float* __restrict__ qw, const float* __restrict__ pw,
                     const float* __restrict__ bt, const int* __restrict__ ri,
                     short* __restrict__ wsw, float* __restrict__ biasf) {
    const int bid = blockIdx.x;
    if (bid < 144) {                       // 144*256*4 = 147456 shorts exact
        const int i = (bid * 256 + threadIdx.x) * 4;
        const float* src = (i < QW_SHORTS) ? (qw + i) : (pw + (i - QW_SHORTS));
        f32x4 v = *(const f32x4*)src;
        short4v o;
        o[0] = f2bf(v[0]); o[1] = f2bf(v[1]); o[2] = f2bf(v[2]); o[3] = f2bf(v[3]);
        *(short4v*)(wsw + i) = o;
    } else {                               // 96*256 = 24576 floats exact
        const int j  = (bid - 144) * 256 + threadIdx.x;
        const int r  = j & 3;
        const int ln = (j >> 2) & 63;
        const int nt = (j >> 8) & 3;
        const int mt = (j >> 10) & 3;
        const int hh = j >> 12;
        const int q  = mt * 16 + (ln & 15);          // q-token row
        const int k  = nt * 16 + (ln >> 4) * 4 + r;  // k-token col
        biasf[j] = bt[ri[q * 64 + k] * HEADS + hh];
    }
}

// LDS: one region [64][200] shorts = 25600 B.
// timeline: x_bf16 (phase 0/1)  --B2-->  o_bf16 (attention/proj)

template <bool WS>
__global__ __launch_bounds__(384, 4) void msa_fused(
    const float* __restrict__ x,
    const short* __restrict__ wq_bf, const short* __restrict__ wp_bf,
    const float* __restrict__ bias_fr,
    const float* __restrict__ wq_f,  const float* __restrict__ wp_f,
    const float* __restrict__ qkv_b, const float* __restrict__ proj_b,
    const float* __restrict__ bias_table, const int* __restrict__ rel_index,
    float* __restrict__ out)
{
    __shared__ __align__(16) short smem[12800];   // [64][200]

    const int tid  = threadIdx.x;
    const int wave = tid >> 6;
    const int lane = tid & 63;
    const int quad = lane >> 4;
    const int l15  = lane & 15;
    const int b    = blockIdx.x;
    const int h    = wave;                        // one head per wave

    // cross-quad gather params: words 0,1 come from src lane srcA,
    // words 2,3 from srcA+16; ct/nt/tt-select by (quad>=2).
    const int  srcA = ((quad & 1) << 5) + l15;
    const bool hiq  = (quad >= 2);

    auto gsel = [&](u32 a, u32 bb, int sl) -> u32 {
        u32 va = (u32)__shfl((int)a, sl, 64);
        u32 vb = (u32)__shfl((int)bb, sl, 64);
        return hiq ? vb : va;
    };
    // sources: p00/p01 = sel0 words, p10/p11 = sel1 words (word = bf16 pair r,r+1)
    auto xpose = [&](u32 p00, u32 p01, u32 p10, u32 p11) -> short8 {
        u32x4 w;
        w[0] = gsel(p00, p10, srcA);
        w[1] = gsel(p01, p11, srcA);
        w[2] = gsel(p00, p10, srcA + 16);
        w[3] = gsel(p01, p11, srcA + 16);
        return __builtin_bit_cast(short8, w);
    };

    // ---- Phase 0: stage x fp32->bf16 into LDS [64][200], coalesced ----
    const float* xg = x + b * (NTOK * DIM);
#pragma unroll
    for (int i = 0; i < 8; ++i) {
        const int f   = tid + i * 384;        // f32x4 index, 0..3071
        f32x4 v = *(const f32x4*)(xg + f * 4);
        const int row = f / 48;               // 48 f32x4 per 192-float row
        const int col = (f % 48) * 4;         // bf16 col
        u32x2 wv; wv[0] = pkbf(v[0], v[1]); wv[1] = pkbf(v[2], v[3]);
        *(u32x2*)(smem + row * 200 + col) = wv;
    }
    __syncthreads();   // B1: x staged

    // ---- Phase 1: per-head QKV ----
    short8 qa[4], kb[4], vfr[2][2];   // q/k A/B frags (lane=token), v B frags [ct][kh]

    // q,k: swapped GEMM  mfma(Wfrag, Xfrag) -> D[(quad,r)=channel][l15=token]
    auto qk_gemm = [&](int wbase, short8 (&fr)[4]) {
        f32x4 acc[2][4];
#pragma unroll
        for (int ct = 0; ct < 2; ++ct)
#pragma unroll
            for (int tt = 0; tt < 4; ++tt) acc[ct][tt] = (f32x4){0.f,0.f,0.f,0.f};
#pragma unroll
        for (int kk = 0; kk < 6; ++kk) {
            short8 xfr[4];
#pragma unroll
            for (int tt = 0; tt < 4; ++tt)
                xfr[tt] = *(const short8*)(smem + (tt*16 + l15)*200 + kk*32 + quad*8);
#pragma unroll
            for (int ct = 0; ct < 2; ++ct) {
                short8 wfr;
                if constexpr (WS) wfr = *(const short8*)(wq_bf + (wbase + ct*16 + l15)*DIM + kk*32 + quad*8);
                else              wfr = ld_cvt8(wq_f + (wbase + ct*16 + l15)*DIM + kk*32 + quad*8);
#pragma unroll
                for (int tt = 0; tt < 4; ++tt)
                    acc[ct][tt] = __builtin_amdgcn_mfma_f32_16x16x32_bf16(wfr, xfr[tt], acc[ct][tt], 0, 0, 0);
            }
        }
        f32x4 bq[2];
        bq[0] = *(const f32x4*)(qkv_b + wbase + quad*4);        // ch = wbase+ct*16+quad*4+r
        bq[1] = *(const f32x4*)(qkv_b + wbase + 16 + quad*4);
#pragma unroll
        for (int ct = 0; ct < 2; ++ct)
#pragma unroll
            for (int tt = 0; tt < 4; ++tt) acc[ct][tt] += bq[ct];
#pragma unroll
        for (int tt = 0; tt < 4; ++tt) {
            u32 p00 = pkbf(acc[0][tt][0], acc[0][tt][1]);
            u32 p01 = pkbf(acc[0][tt][2], acc[0][tt][3]);
            u32 p10 = pkbf(acc[1][tt][0], acc[1][tt][1]);
            u32 p11 = pkbf(acc[1][tt][2], acc[1][tt][3]);
            fr[tt] = xpose(p00, p01, p10, p11);   // lane=token, elem=8 channels
        }
    };
    qk_gemm(h*32,       qa);
    qk_gemm(192 + h*32, kb);

    // v: normal GEMM  mfma(Xfrag, Wfrag) -> D[(quad,r)=token][l15=channel]
    {
        f32x4 acc[4][2];   // [tt][ct]
#pragma unroll
        for (int tt = 0; tt < 4; ++tt)
#pragma unroll
            for (int ct = 0; ct < 2; ++ct) acc[tt][ct] = (f32x4){0.f,0.f,0.f,0.f};
#pragma unroll
        for (int kk = 0; kk < 6; ++kk) {
            short8 xfr[4];
#pragma unroll
            for (int tt = 0; tt < 4; ++tt)
                xfr[tt] = *(const short8*)(smem + (tt*16 + l15)*200 + kk*32 + quad*8);
#pragma unroll
            for (int ct = 0; ct < 2; ++ct) {
                const int wrow = 384 + h*32 + ct*16 + l15;
                short8 wfr;
                if constexpr (WS) wfr = *(const short8*)(wq_bf + wrow*DIM + kk*32 + quad*8);
                else              wfr = ld_cvt8(wq_f + wrow*DIM + kk*32 + quad*8);
#pragma unroll
                for (int tt = 0; tt < 4; ++tt)
                    acc[tt][ct] = __builtin_amdgcn_mfma_f32_16x16x32_bf16(xfr[tt], wfr, acc[tt][ct], 0, 0, 0);
            }
        }
        const float bv0 = qkv_b[384 + h*32 + l15];
        const float bv1 = qkv_b[384 + h*32 + 16 + l15];
        u32 pkv[2][4][2];
#pragma unroll
        for (int tt = 0; tt < 4; ++tt) {
#pragma unroll
            for (int r = 0; r < 4; ++r) { acc[tt][0][r] += bv0; acc[tt][1][r] += bv1; }
#pragma unroll
            for (int ct = 0; ct < 2; ++ct) {
                pkv[ct][tt][0] = pkbf(acc[tt][ct][0], acc[tt][ct][1]);
                pkv[ct][tt][1] = pkbf(acc[tt][ct][2], acc[tt][ct][3]);
            }
        }
#pragma unroll
        for (int ct = 0; ct < 2; ++ct)
#pragma unroll
            for (int kh = 0; kh < 2; ++kh)
                vfr[ct][kh] = xpose(pkv[ct][2*kh][0], pkv[ct][2*kh][1],
                                    pkv[ct][2*kh+1][0], pkv[ct][2*kh+1][1]);
    }
    __syncthreads();   // B2: all waves done reading x region -> reuse as o

    // ---- Phase 2: attention (all in registers; o tile -> LDS per mt) ----
    const float scale = 0.17677669529663687f;   // 32^-0.5
    const float L2E   = 1.44269504088896f;
#pragma unroll
    for (int mt = 0; mt < 4; ++mt) {
        // swapped QK^T: D[(quad,r)=k-token][l15=q-token]; lane holds full k-row
        f32x4 s[4];
#pragma unroll
        for (int nt = 0; nt < 4; ++nt) {
            f32x4 z = (f32x4){0.f,0.f,0.f,0.f};
            s[nt] = __builtin_amdgcn_mfma_f32_16x16x32_bf16(kb[nt], qa[mt], z, 0, 0, 0);
        }
        if constexpr (WS) {
#pragma unroll
            for (int nt = 0; nt < 4; ++nt) {
                f32x4 bb = *(const f32x4*)(bias_fr + ((((h*4 + mt)*4 + nt)*64 + lane) << 2));
#pragma unroll
                for (int r = 0; r < 4; ++r) s[nt][r] = s[nt][r]*scale + bb[r];
            }
        } else {
#pragma unroll
            for (int nt = 0; nt < 4; ++nt)
#pragma unroll
                for (int r = 0; r < 4; ++r) {
                    const int q = mt*16 + l15, k = nt*16 + quad*4 + r;
                    s[nt][r] = s[nt][r]*scale + bias_table[rel_index[q*64 + k]*HEADS + h];
                }
        }
        // softmax over k: 16 lane-local + 2 cross-quad shuffles
        float m = -1e30f;
#pragma unroll
        for (int nt = 0; nt < 4; ++nt)
#pragma unroll
            for (int r = 0; r < 4; ++r) m = fmaxf(m, s[nt][r]);
        m = fmaxf(m, __shfl_xor(m, 16)); m = fmaxf(m, __shfl_xor(m, 32));
        float sum = 0.f;
#pragma unroll
        for (int nt = 0; nt < 4; ++nt)
#pragma unroll
            for (int r = 0; r < 4; ++r) {
                float e = exp2f((s[nt][r] - m) * L2E);
                s[nt][r] = e; sum += e;
            }
        sum += __shfl_xor(sum, 16); sum += __shfl_xor(sum, 32);
        const float inv = 1.f / sum;
        u32 pk[4][2];
#pragma unroll
        for (int nt = 0; nt < 4; ++nt) {
            pk[nt][0] = pkbf(s[nt][0]*inv, s[nt][1]*inv);
            pk[nt][1] = pkbf(s[nt][2]*inv, s[nt][3]*inv);
        }
        // PV: pfr = P A-frag (lane=q, elem=k) via same cross-quad gather
        f32x4 oa[2];
        oa[0] = (f32x4){0.f,0.f,0.f,0.f}; oa[1] = (f32x4){0.f,0.f,0.f,0.f};
#pragma unroll
        for (int kh = 0; kh < 2; ++kh) {
            short8 pfr = xpose(pk[2*kh][0], pk[2*kh][1], pk[2*kh+1][0], pk[2*kh+1][1]);
#pragma unroll
            for (int ct = 0; ct < 2; ++ct)
                oa[ct] = __builtin_amdgcn_mfma_f32_16x16x32_bf16(pfr, vfr[ct][kh], oa[ct], 0, 0, 0);
        }
        // o tile -> LDS [64][200]: rows=(quad,r)+mt*16, cols = head channels
#pragma unroll
        for (int ct = 0; ct < 2; ++ct)
#pragma unroll
            for (int r = 0; r < 4; ++r)
                smem[(mt*16 + quad*4 + r)*200 + h*32 + ct*16 + l15] = f2bf(oa[ct][r]);
    }
    __syncthreads();   // B3: o complete

    // ---- Phase 3: output projection (wave h -> out channels [h*32,h*32+32)) ----
    float* outg = out + b * (NTOK * DIM);
#pragma unroll
    for (int nt2 = 0; nt2 < 2; ++nt2) {
        const int c0 = h*32 + nt2*16;
        f32x4 acc[4];
#pragma unroll
        for (int tt = 0; tt < 4; ++tt) acc[tt] = (f32x4){0.f,0.f,0.f,0.f};
#pragma unroll
        for (int kk = 0; kk < 6; ++kk) {
            short8 ofr[4];
#pragma unroll
            for (int tt = 0; tt < 4; ++tt)
                ofr[tt] = *(const short8*)(smem + (tt*16 + l15)*200 + kk*32 + quad*8);
            short8 wfr;
            if constexpr (WS) wfr = *(const short8*)(wp_bf + (c0 + l15)*DIM + kk*32 + quad*8);
            else              wfr = ld_cvt8(wp_f + (c0 + l15)*DIM + kk*32 + quad*8);
#pragma unroll
            for (int tt = 0; tt < 4; ++tt)
                acc[tt] = __builtin_amdgcn_mfma_f32_16x16x32_bf16(ofr[tt], wfr, acc[tt], 0, 0, 0);
        }
        const float pb = proj_b[c0 + l15];
#pragma unroll
        for (int tt = 0; tt < 4; ++tt)
#pragma unroll
            for (int r = 0; r < 4; ++r) {
                float sv = acc[tt][r] + pb;
                if (!(__builtin_fabsf(sv) < 1e30f)) sv = 0.f;   // sanitize (diagnostic)
                outg[(tt*16 + quad*4 + r)*DIM + c0 + l15] = sv;
            }
    }
}

extern "C" void kernel_launch(void* const* d_in, const int* in_sizes, int n_in,
                              void* d_out, int out_size, void* d_ws, size_t ws_size,
                              hipStream_t stream) {
    const float* x          = (const float*)d_in[0];
    const float* qkv_w      = (const float*)d_in[1];
    const float* qkv_b      = (const float*)d_in[2];
    const float* proj_w     = (const float*)d_in[3];
    const float* proj_b     = (const float*)d_in[4];
    const float* bias_table = (const float*)d_in[5];
    const int*   rel_index  = (const int*)d_in[6];
    float* out = (float*)d_out;

    if (ws_size >= (size_t)WS_NEEDED) {
        short* wsw   = (short*)d_ws;
        float* biasf = (float*)((char*)d_ws + BIAS_OFF_B);
        prep<<<240, 256, 0, stream>>>(qkv_w, proj_w, bias_table, rel_index, wsw, biasf);
        msa_fused<true><<<NWIN, 384, 0, stream>>>(
            x, wsw, wsw + QW_SHORTS, biasf, qkv_w, proj_w,
            qkv_b, proj_b, bias_table, rel_index, out);
    } else {
        msa_fused<false><<<NWIN, 384, 0, stream>>>(
            x, nullptr, nullptr, nullptr, qkv_w, proj_w,
            qkv_b, proj_b, bias_table, rel_index, out);
    }
}